// Round 2
// baseline (175.622 us; speedup 1.0000x reference)
//
#include <hip/hip_runtime.h>

// Keep float semantics deterministic (no FMA contraction anywhere).
#pragma clang fp contract(off)

#define DD 128
#define NCELL (DD * DD * DD)
#define CELLS_PER_THREAD 4

__global__ __launch_bounds__(256) void cafe_rnn_kernel(
    const float* __restrict__ x,    // [NCELL][5]  : state0, e0,e1,e2, field0(unused)
    const float* __restrict__ out,  // [NCELL][8]  : logits0..3, rot0..2, field
    float* __restrict__ y)          // [NCELL][5]  : state1, e0,e1,e2, field1
{
    const int t  = blockIdx.x * blockDim.x + threadIdx.x;
    const int n0 = t * CELLS_PER_THREAD;
    if (n0 >= NCELL) return;

    // ---- vectorized loads: 4 cells per thread ----
    // x:   4 cells * 5 f32 = 20 f32 = 5 float4 (16B aligned per thread)
    // out: 4 cells * 8 f32 = 32 f32 = 8 float4
    float4 xa[5], oa[8];
    const float4* xp = reinterpret_cast<const float4*>(x) + (size_t)t * 5;
    const float4* op = reinterpret_cast<const float4*>(out) + (size_t)t * 8;
#pragma unroll
    for (int q = 0; q < 5; ++q) xa[q] = xp[q];
#pragma unroll
    for (int q = 0; q < 8; ++q) oa[q] = op[q];

    float xv[20], ov[32], rv[20];
#pragma unroll
    for (int q = 0; q < 5; ++q) {
        xv[q * 4 + 0] = xa[q].x; xv[q * 4 + 1] = xa[q].y;
        xv[q * 4 + 2] = xa[q].z; xv[q * 4 + 3] = xa[q].w;
    }
#pragma unroll
    for (int q = 0; q < 8; ++q) {
        ov[q * 4 + 0] = oa[q].x; ov[q * 4 + 1] = oa[q].y;
        ov[q * 4 + 2] = oa[q].z; ov[q * 4 + 3] = oa[q].w;
    }

#pragma unroll
    for (int c = 0; c < CELLS_PER_THREAD; ++c) {
        const int s0 = (int)xv[c * 5 + 0];

        // argmax over out[..., 0:4], first-occurrence semantics (strict >)
        float b = ov[c * 8 + 0];
        int   s1 = 0;
        if (ov[c * 8 + 1] > b) { b = ov[c * 8 + 1]; s1 = 1; }
        if (ov[c * 8 + 2] > b) { b = ov[c * 8 + 2]; s1 = 2; }
        if (ov[c * 8 + 3] > b) { b = ov[c * 8 + 3]; s1 = 3; }
        if (s0 == 0) s1 = 0;

        float f1 = ov[c * 8 + 7];
        float e0 = xv[c * 5 + 1], e1 = xv[c * 5 + 2], e2 = xv[c * 5 + 3];

        if (s1 <= 1) {
            f1 = -1.0f; e0 = -1.0f; e1 = -1.0f; e2 = -1.0f;
        } else if (s1 == 2) {
            f1 = fminf(fmaxf(f1, 0.0f), 0.92f);
        } else { // s1 == 3
            f1 = 1.0f;
        }

        // flag_solidify = state0<=1 && state1>1  (lazy 26-neighbor argmin)
        if (s0 <= 1 && s1 > 1) {
            const int n = n0 + c;
            const int k = n & (DD - 1);
            const int j = (n >> 7) & (DD - 1);
            const int i = (n >> 14);
            // f64 distances: exact diffs (f32 exactly representable in f64),
            // ordering matches a float64 numpy reference argmin.
            const double r0 = (double)ov[c * 8 + 4];
            const double r1 = (double)ov[c * 8 + 5];
            const double r2 = (double)ov[c * 8 + 6];

            double best = 1.0e300;
            float ce0 = 0.0f, ce1 = 0.0f, ce2 = 0.0f;
#pragma unroll
            for (int di = -1; di <= 1; ++di) {
#pragma unroll
                for (int dj = -1; dj <= 1; ++dj) {
#pragma unroll
                    for (int dk = -1; dk <= 1; ++dk) {
                        if (di == 0 && dj == 0 && dk == 0) continue;
                        const int ii = i + di, jj = j + dj, kk = k + dk;
                        float a0 = 0.0f, a1 = 0.0f, a2 = 0.0f;
                        if ((unsigned)ii < (unsigned)DD &&
                            (unsigned)jj < (unsigned)DD &&
                            (unsigned)kk < (unsigned)DD) {
                            const float* p = x + ((size_t)((ii * DD + jj) * DD + kk)) * 5 + 1;
                            a0 = p[0]; a1 = p[1]; a2 = p[2];
                        }
                        const double d0 = (double)a0 - r0;
                        const double d1 = (double)a1 - r1;
                        const double d2 = (double)a2 - r2;
                        const double dist = d0 * d0 + d1 * d1 + d2 * d2;
                        if (dist < best) { best = dist; ce0 = a0; ce1 = a1; ce2 = a2; }
                    }
                }
            }
            e0 = ce0; e1 = ce1; e2 = ce2;
        }

        rv[c * 5 + 0] = (float)s1;
        rv[c * 5 + 1] = e0;
        rv[c * 5 + 2] = e1;
        rv[c * 5 + 3] = e2;
        rv[c * 5 + 4] = f1;
    }

    // ---- vectorized store: 5 float4 ----
    float4* yp = reinterpret_cast<float4*>(y) + (size_t)t * 5;
#pragma unroll
    for (int q = 0; q < 5; ++q) {
        float4 v;
        v.x = rv[q * 4 + 0]; v.y = rv[q * 4 + 1];
        v.z = rv[q * 4 + 2]; v.w = rv[q * 4 + 3];
        yp[q] = v;
    }
}

extern "C" void kernel_launch(void* const* d_in, const int* in_sizes, int n_in,
                              void* d_out, int out_size, void* d_ws, size_t ws_size,
                              hipStream_t stream) {
    const float* x   = (const float*)d_in[0];
    const float* out = (const float*)d_in[1];
    float* y = (float*)d_out;

    const int threads = 256;
    const int total_threads = NCELL / CELLS_PER_THREAD; // 524288
    const int blocks = total_threads / threads;         // 2048
    cafe_rnn_kernel<<<blocks, threads, 0, stream>>>(x, out, y);
}